// Round 15
// baseline (1041.178 us; speedup 1.0000x reference)
//
#include <hip/hip_runtime.h>
#include <hip/hip_bf16.h>

#define T_TOK  2048
#define DIMSZ  2048
#define NEXP   32
#define INTERS 1024
#define SINTER 2048
#define NTOPK  6

typedef __bf16 bf16x8 __attribute__((ext_vector_type(8)));
typedef float  f32x4  __attribute__((ext_vector_type(4)));
typedef unsigned short u16x8 __attribute__((ext_vector_type(8)));

__device__ __forceinline__ unsigned short f2b(float f) {
    __hip_bfloat16 h = __float2bfloat16(f);
    return __builtin_bit_cast(unsigned short, h);
}

// async global->LDS, 16B per lane. LDS dest is wave-uniform base + lane*16.
__device__ __forceinline__ void gl_lds16(const unsigned short* g, unsigned short* l) {
    __builtin_amdgcn_global_load_lds(
        (const __attribute__((address_space(1))) void*)g,
        (__attribute__((address_space(3))) void*)l, 16, 0, 0);
}
__device__ __forceinline__ void gl_lds16f(const float* g, float* l) {
    __builtin_amdgcn_global_load_lds(
        (const __attribute__((address_space(1))) void*)g,
        (__attribute__((address_space(3))) void*)l, 16, 0, 0);
}

// 8 f32 -> bf16x8 fragment
__device__ __forceinline__ bf16x8 cvt8(float4 lo, float4 hi) {
    u16x8 u;
    u[0] = f2b(lo.x); u[1] = f2b(lo.y); u[2] = f2b(lo.z); u[3] = f2b(lo.w);
    u[4] = f2b(hi.x); u[5] = f2b(hi.y); u[6] = f2b(hi.z); u[7] = f2b(hi.w);
    return __builtin_bit_cast(bf16x8, u);
}

// ---------------- x -> bf16 (only conversion pass, 16 MB) ----------------
__global__ void cvt_f2b(const float4* __restrict__ src, unsigned short* __restrict__ dst, int n8) {
    int stride = gridDim.x * blockDim.x;
    for (int i = blockIdx.x * blockDim.x + threadIdx.x; i < n8; i += stride) {
        float4 a = src[2 * (size_t)i];
        float4 b = src[2 * (size_t)i + 1];
        u16x8 o;
        o[0] = f2b(a.x); o[1] = f2b(a.y); o[2] = f2b(a.z); o[3] = f2b(a.w);
        o[4] = f2b(b.x); o[5] = f2b(b.y); o[6] = f2b(b.z); o[7] = f2b(b.w);
        *(u16x8*)&dst[(size_t)i * 8] = o;
    }
}

// ---------------- gate scores: scores[T,E] = sigmoid(x @ gw^T), fp32 ----------------
#define SCT 8
#define SCK 128
__global__ __launch_bounds__(256) void gate_scores_kernel(
    const float* __restrict__ x, const float* __restrict__ gw, float* __restrict__ scores)
{
    __shared__ float xs[SCT * SCK];            // 8 x 128
    __shared__ float gs[NEXP * (SCK + 1)];     // 32 x 129 (pad: conflict-free)
    const int t0 = blockIdx.x * SCT;
    const int tid = threadIdx.x;
    const int tl = tid >> 5, e = tid & 31;
    float acc = 0.f;
    for (int k0 = 0; k0 < DIMSZ; k0 += SCK) {
        {
            int row = tid >> 5, d4 = tid & 31;
            *(float4*)&xs[row * SCK + d4 * 4] =
                *(const float4*)&x[(size_t)(t0 + row) * DIMSZ + k0 + d4 * 4];
        }
        #pragma unroll
        for (int i = 0; i < 4; ++i) {
            int lin = tid + i * 256;
            int row = lin >> 5, d4 = lin & 31;
            float4 v = *(const float4*)&gw[(size_t)row * DIMSZ + k0 + d4 * 4];
            float* dst = &gs[row * (SCK + 1) + d4 * 4];
            dst[0] = v.x; dst[1] = v.y; dst[2] = v.z; dst[3] = v.w;
        }
        __syncthreads();
        #pragma unroll 8
        for (int d = 0; d < SCK; ++d)
            acc += xs[tl * SCK + d] * gs[e * (SCK + 1) + d];
        __syncthreads();
    }
    scores[(size_t)(t0 + tl) * NEXP + e] = 1.f / (1.f + expf(-acc));
}

// ---------------- top-k routing (one thread per token) ----------------
__global__ __launch_bounds__(256) void topk_kernel(
    const float* __restrict__ scores,
    int* __restrict__ counts, int* __restrict__ toklist, float* __restrict__ wgts)
{
    int t = blockIdx.x * 256 + threadIdx.x;
    if (t >= T_TOK) return;
    float sc[NEXP];
    #pragma unroll
    for (int e = 0; e < NEXP; ++e) sc[e] = scores[(size_t)t * NEXP + e];

    float gsc[8];
    #pragma unroll
    for (int g = 0; g < 8; ++g) {
        float m = sc[4 * g];
        #pragma unroll
        for (int j = 1; j < 4; ++j) m = fmaxf(m, sc[4 * g + j]);
        gsc[g] = m;
    }
    bool gsel[8] = {false, false, false, false, false, false, false, false};
    for (int it = 0; it < 4; ++it) {
        int bi = -1; float bv = -1e30f;
        #pragma unroll
        for (int g = 0; g < 8; ++g)
            if (!gsel[g] && gsc[g] > bv) { bv = gsc[g]; bi = g; }
        gsel[bi] = true;
    }
    bool esel[NEXP];
    #pragma unroll
    for (int e = 0; e < NEXP; ++e) esel[e] = false;
    int   idx[NTOPK];
    float w[NTOPK];
    float sum = 0.f;
    for (int it = 0; it < NTOPK; ++it) {
        int bi = -1; float bv = -1e30f;
        #pragma unroll
        for (int e = 0; e < NEXP; ++e) {
            if (!gsel[e >> 2] || esel[e]) continue;
            if (sc[e] > bv) { bv = sc[e]; bi = e; }
        }
        esel[bi] = true; idx[it] = bi; w[it] = bv; sum += bv;
    }
    float scale = 2.5f / sum;
    for (int k = 0; k < NTOPK; ++k) {
        int e = idx[k];
        int s = atomicAdd(&counts[e], 1);
        toklist[e * T_TOK + s] = (t << 3) | k;
        wgts[e * T_TOK + s]   = w[k] * scale;
    }
}

// per-thread (uniform) tile decode for fc2: shared first (BN=128), routed expert-major
__device__ __forceinline__ void decode_tile(
    int wgid, int xt_bits, const int* __restrict__ counts,
    bool& SH, int& e, int& m0, int& n0)
{
    if (wgid < 256) {
        SH = true; e = NEXP; m0 = (wgid >> 4) * 128; n0 = (wgid & 15) * 128;
        return;
    }
    const int rid = wgid - 256;
    const int xmask = (1 << xt_bits) - 1;
    const int xt = rid & xmask, ty = rid >> xt_bits;
    int acc2 = 0, fe = -1, fy = 0;
    #pragma unroll
    for (int e2 = 0; e2 < NEXP; ++e2) {
        const int nt = (counts[e2] + 127) >> 7;
        if (fe < 0 && ty < acc2 + nt) { fe = e2; fy = ty - acc2; }
        acc2 += nt;
    }
    SH = false; e = fe; m0 = fy * 128; n0 = xt * 128;
}

// =======================================================================
// fc1_all: UNCHANGED from round 14 (291 us, best). Tile 128x64, wave
// grid 2x2, 64-reg acc, BK=64, LDS 48 KB -> 3 blocks/CU.
// A bf16 gl_lds [128x64]; B1/B2 raw f32 gl_lds [64x64], cvt on read.
// H = silu(A@B1^T) * (A@B2^T), bf16 out.
// =======================================================================
__global__ __launch_bounds__(256, 3) void fc1_all(
    const unsigned short* __restrict__ A,
    const float* __restrict__ w11, const float* __restrict__ w33,
    const float* __restrict__ sw1, const float* __restrict__ sw3,
    unsigned short* __restrict__ h, unsigned short* __restrict__ hs,
    const int* __restrict__ counts, const int* __restrict__ toklist)
{
    constexpr int BK = 64, K = DIMSZ, NT = K / BK;
    __shared__ unsigned short As[128 * 64];   // 16 KB
    __shared__ float B1s[64 * 64];            // 16 KB
    __shared__ float B2s[64 * 64];            // 16 KB

    const int tid = threadIdx.x;
    bool SH; int e, m0, n0;
    {
        const int wgid = blockIdx.x;
        if (wgid < 512) {            // shared: 16y x 32x tiles of 128x64
            SH = true; e = NEXP; m0 = (wgid >> 5) * 128; n0 = (wgid & 31) * 64;
        } else {                     // routed: 16 x-tiles of 64, expert-major
            const int rid = wgid - 512;
            const int xt = rid & 15, ty = rid >> 4;
            int acc2 = 0, fe = -1, fy = 0;
            #pragma unroll
            for (int e2 = 0; e2 < NEXP; ++e2) {
                const int nt = (counts[e2] + 127) >> 7;
                if (fe < 0 && ty < acc2 + nt) { fe = e2; fy = ty - acc2; }
                acc2 += nt;
            }
            SH = false; e = fe; m0 = fy * 128; n0 = xt * 64;
        }
    }
    if (!SH && e < 0) return;
    const int N = SH ? SINTER : INTERS;
    const int M = SH ? T_TOK : counts[e];

    const size_t eoff = SH ? 0 : (size_t)e * INTERS * DIMSZ;
    const float* B1 = (SH ? sw1 : w11) + eoff + (size_t)n0 * K;
    const float* B2 = (SH ? sw3 : w33) + eoff + (size_t)n0 * K;
    unsigned short* Hout = SH ? hs : h;

    const int wave = tid >> 6;
    const int lane = tid & 63;
    const int wm = (wave >> 1) * 64;          // 2x2 wave grid over 128x64
    const int wn = (wave & 1) * 32;
    const int lm = lane & 15;
    const int quad = lane >> 4;

    // A: 16 chunks of 8 rows x 64 bf16; 4 per wave
    const unsigned short* aP[4];
    {
        const int l8 = lane >> 3;
        const int sg = (lane & 7) ^ l8;       // pre-swizzled 16B granule
        #pragma unroll
        for (int i = 0; i < 4; ++i) {
            const int row = (wave * 4 + i) * 8 + l8;
            const int gr = m0 + row;
            int ar;
            if (SH) ar = gr;
            else ar = (gr < M) ? (toklist[e * T_TOK + gr] >> 3) : 0;
            aP[i] = A + (size_t)ar * K + sg * 8;
        }
    }
    // B: 16 chunks of 4 rows x 64 f32; 4 per wave
    int offB[4];
    {
        #pragma unroll
        for (int i = 0; i < 4; ++i) {
            const int c = wave * 4 + i;
            const int row = 4 * c + (lane >> 4);
            const int g = (lane & 15) ^ (row & 7);
            offB[i] = row * K + g * 4;
        }
    }

    f32x4 acc1[4][2] = {};
    f32x4 acc2v[4][2] = {};

    for (int t = 0; t < NT; ++t) {
        const int k0 = t * BK;
        #pragma unroll
        for (int i = 0; i < 4; ++i)
            gl_lds16(aP[i] + k0, &As[(wave * 4 + i) * 512]);
        #pragma unroll
        for (int i = 0; i < 4; ++i) {
            gl_lds16f(B1 + offB[i] + k0, &B1s[(wave * 4 + i) * 256]);
            gl_lds16f(B2 + offB[i] + k0, &B2s[(wave * 4 + i) * 256]);
        }
        __syncthreads();   // drains vmcnt(0): all DMA visible

        #pragma unroll
        for (int kh = 0; kh < 2; ++kh) {
            const int soffA = (((kh << 2) | quad) ^ (lm & 7)) << 3;
            const int j0 = ((kh << 2) | quad) << 1;
            const int s0 = j0 ^ (lm & 7);
            const int s1 = (j0 | 1) ^ (lm & 7);
            bf16x8 af[4], bf1[2], bf2[2];
            #pragma unroll
            for (int ti = 0; ti < 4; ++ti)
                af[ti] = *(const bf16x8*)&As[(wm + ti * 16 + lm) * 64 + soffA];
            #pragma unroll
            for (int tj = 0; tj < 2; ++tj) {
                const int rB = (wn + tj * 16 + lm) * 64;
                bf1[tj] = cvt8(*(const float4*)&B1s[rB + s0 * 4],
                               *(const float4*)&B1s[rB + s1 * 4]);
                bf2[tj] = cvt8(*(const float4*)&B2s[rB + s0 * 4],
                               *(const float4*)&B2s[rB + s1 * 4]);
            }
            #pragma unroll
            for (int ti = 0; ti < 4; ++ti)
                #pragma unroll
                for (int tj = 0; tj < 2; ++tj) {
                    acc1[ti][tj] = __builtin_amdgcn_mfma_f32_16x16x32_bf16(
                        af[ti], bf1[tj], acc1[ti][tj], 0, 0, 0);
                    acc2v[ti][tj] = __builtin_amdgcn_mfma_f32_16x16x32_bf16(
                        af[ti], bf2[tj], acc2v[ti][tj], 0, 0, 0);
                }
        }
        __syncthreads();
    }

    #pragma unroll
    for (int ti = 0; ti < 4; ++ti) {
        #pragma unroll
        for (int r = 0; r < 4; ++r) {
            const int lrow = wm + ti * 16 + quad * 4 + r;
            const int grow = m0 + lrow;
            int cr;
            if (SH) cr = grow;
            else {
                if (grow >= M) continue;
                int ent = toklist[e * T_TOK + grow];
                cr = (ent >> 3) * NTOPK + (ent & 7);
            }
            #pragma unroll
            for (int tj = 0; tj < 2; ++tj) {
                int nn = n0 + wn + tj * 16 + lm;
                float g = acc1[ti][tj][r];
                float u = acc2v[ti][tj][r];
                float hv = g / (1.f + expf(-g)) * u;
                Hout[(size_t)cr * N + nn] = f2b(hv);
            }
        }
    }
}

// =======================================================================
// fc2_all: BK=64 (ported from fc1's validated cadence win; body is the
// round-9-verified layout). LDS 16+32 = 48 KB -> 3 blocks/CU, 64-reg acc.
// MODE 0: merged dense (shared->out, routed->yexp slot).
// MODE 1: shared only.  MODE 2: routed only, atomic into out.
// =======================================================================
template <int MODE>
__global__ __launch_bounds__(256, 3) void fc2_all(
    const unsigned short* __restrict__ h, const unsigned short* __restrict__ hs,
    const float* __restrict__ w22, const float* __restrict__ sw2,
    float* __restrict__ yexp, float* __restrict__ out,
    const int* __restrict__ counts, const int* __restrict__ toklist,
    const float* __restrict__ wgts)
{
    constexpr int BK = 64;
    __shared__ unsigned short As[128 * 64];   // 16 KB
    __shared__ float Bs[128 * 64];            // 32 KB

    const int tid = threadIdx.x;
    bool SH; int e, m0, n0;
    {
        int wgid = blockIdx.x;
        if (MODE == 1) { SH = true; e = NEXP; m0 = (wgid >> 4) * 128; n0 = (wgid & 15) * 128; }
        else if (MODE == 2) { decode_tile(wgid + 256, 4, counts, SH, e, m0, n0); }
        else decode_tile(wgid, 4, counts, SH, e, m0, n0);   // routed: 16 x-tiles
    }
    if (!SH && e < 0) return;
    const int K = SH ? SINTER : INTERS;
    const int NT = K / BK;
    const int M = SH ? T_TOK : counts[e];
    if (m0 >= M) return;

    const unsigned short* Asrc = SH ? hs : h;   // row stride == K
    const float* B = (SH ? sw2 : (w22 + (size_t)e * DIMSZ * INTERS)) + (size_t)n0 * K;
    float* C = SH ? out : ((MODE == 2) ? out : yexp);

    const int wave = tid >> 6;
    const int lane = tid & 63;
    const int wm = (wave >> 1) * 64;
    const int wn = (wave & 1) * 64;
    const int lm = lane & 15;
    const int quad = lane >> 4;

    // A: 16 chunks of 8 rows x 64 bf16; 4 per wave (r9-verified)
    const unsigned short* aP[4];
    {
        const int l8 = lane >> 3;
        const int sg = (lane & 7) ^ l8;
        #pragma unroll
        for (int i = 0; i < 4; ++i) {
            const int row = (wave * 4 + i) * 8 + l8;
            const int gr = m0 + row;
            int ar;
            if (SH) ar = gr;
            else if (gr < M) {
                int ent = toklist[e * T_TOK + gr];
                ar = (ent >> 3) * NTOPK + (ent & 7);
            } else ar = 0;
            aP[i] = Asrc + (size_t)ar * K + sg * 8;
        }
    }
    // B: 32 chunks of 4 rows x 64 f32; 8 per wave (r9-verified)
    int offB[8];
    {
        #pragma unroll
        for (int i = 0; i < 8; ++i) {
            const int c = wave * 8 + i;
            const int row = 4 * c + (lane >> 4);
            const int g = (lane & 15) ^ (row & 7);
            offB[i] = row * K + g * 4;
        }
    }

    f32x4 acc[4][4] = {};

    for (int t = 0; t < NT; ++t) {
        const int k0 = t * BK;
        #pragma unroll
        for (int i = 0; i < 4; ++i)
            gl_lds16(aP[i] + k0, &As[(wave * 4 + i) * 512]);
        #pragma unroll
        for (int i = 0; i < 8; ++i) {
            const int c = wave * 8 + i;
            gl_lds16f(B + offB[i] + k0, &Bs[c * 256]);
        }
        __syncthreads();

        #pragma unroll
        for (int kh = 0; kh < 2; ++kh) {
            const int soffA = (((kh << 2) | quad) ^ (lm & 7)) << 3;
            const int j0 = ((kh << 2) | quad) << 1;
            const int s0 = j0 ^ (lm & 7);
            const int s1 = (j0 | 1) ^ (lm & 7);
            bf16x8 af[4], bfr[4];
            #pragma unroll
            for (int ti = 0; ti < 4; ++ti)
                af[ti] = *(const bf16x8*)&As[(wm + ti * 16 + lm) * 64 + soffA];
            #pragma unroll
            for (int tj = 0; tj < 4; ++tj) {
                const int rB = (wn + tj * 16 + lm) * 64;
                bfr[tj] = cvt8(*(const float4*)&Bs[rB + s0 * 4],
                               *(const float4*)&Bs[rB + s1 * 4]);
            }
            #pragma unroll
            for (int ti = 0; ti < 4; ++ti)
                #pragma unroll
                for (int tj = 0; tj < 4; ++tj)
                    acc[ti][tj] = __builtin_amdgcn_mfma_f32_16x16x32_bf16(
                        af[ti], bfr[tj], acc[ti][tj], 0, 0, 0);
        }
        __syncthreads();
    }

    #pragma unroll
    for (int ti = 0; ti < 4; ++ti) {
        #pragma unroll
        for (int r = 0; r < 4; ++r) {
            const int lrow = wm + ti * 16 + quad * 4 + r;
            const int grow = m0 + lrow;
            int cr; float cw;
            if (SH) { cr = grow; cw = 1.f; }
            else {
                if (grow >= M) continue;
                int ent = toklist[e * T_TOK + grow];
                cr = (MODE == 2) ? (ent >> 3) : ((ent >> 3) * NTOPK + (ent & 7));
                cw = wgts[e * T_TOK + grow];
            }
            #pragma unroll
            for (int tj = 0; tj < 4; ++tj) {
                int nn = n0 + wn + tj * 16 + lm;
                float v = acc[ti][tj][r] * cw;
                if (MODE == 2 && !SH)
                    atomicAdd(&C[(size_t)cr * DIMSZ + nn], v);
                else
                    C[(size_t)cr * DIMSZ + nn] = v;
            }
        }
    }
}

// ---------------- combine: out[t,:] += sum_k yexp[t*6+k,:] ----------------
__global__ __launch_bounds__(256) void combine_kernel(
    const float4* __restrict__ yexp, float4* __restrict__ out, int n4)
{
    const int D4 = DIMSZ / 4;   // 512
    int stride = gridDim.x * blockDim.x;
    for (int i = blockIdx.x * blockDim.x + threadIdx.x; i < n4; i += stride) {
        int t = i / D4, d4 = i - t * D4;
        const float4* r = yexp + (size_t)t * NTOPK * D4 + d4;
        float4 a = out[i];
        #pragma unroll
        for (int k = 0; k < NTOPK; ++k) {
            float4 s = r[(size_t)k * D4];
            a.x += s.x; a.y += s.y; a.z += s.z; a.w += s.w;
        }
        out[i] = a;
    }
}

extern "C" void kernel_launch(void* const* d_in, const int* in_sizes, int n_in,
                              void* d_out, int out_size, void* d_ws, size_t ws_size,
                              hipStream_t stream)
{
    const float* x   = (const float*)d_in[0];
    const float* gw  = (const float*)d_in[1];
    const float* w11 = (const float*)d_in[2];
    const float* w33 = (const float*)d_in[3];
    const float* w22 = (const float*)d_in[4];
    const float* sw1 = (const float*)d_in[5];
    const float* sw2 = (const float*)d_in[6];
    const float* sw3 = (const float*)d_in[7];
    float* out = (float*)d_out;

    char* ws = (char*)d_ws;
    size_t off = 0;
    auto alloc = [&](size_t b) { void* p = ws + off; off = (off + b + 255) & ~(size_t)255; return p; };
    int*            counts  = (int*)alloc(NEXP * 4);
    int*            toklist = (int*)alloc((size_t)NEXP * T_TOK * 4);
    float*          wgts    = (float*)alloc((size_t)NEXP * T_TOK * 4);
    float*          scores  = (float*)alloc((size_t)T_TOK * NEXP * 4);
    unsigned short* xb      = (unsigned short*)alloc((size_t)T_TOK * DIMSZ * 2);
    unsigned short* h       = (unsigned short*)alloc((size_t)T_TOK * NTOPK * INTERS * 2);
    unsigned short* hs      = (unsigned short*)alloc((size_t)T_TOK * SINTER * 2);

    const size_t yBytes = (size_t)T_TOK * NTOPK * DIMSZ * 4;   // 100.7 MB
    const bool DENSE = (off + yBytes + 256) <= ws_size;
    float* yexp = DENSE ? (float*)alloc(yBytes) : nullptr;

    hipMemsetAsync(counts, 0, NEXP * 4, stream);

    const int n4x = T_TOK * DIMSZ / 4;
    cvt_f2b<<<1024, 256, 0, stream>>>((const float4*)x, xb, T_TOK * DIMSZ / 8);

    gate_scores_kernel<<<T_TOK / SCT, 256, 0, stream>>>(x, gw, scores);
    topk_kernel<<<(T_TOK + 255) / 256, 256, 0, stream>>>(scores, counts, toklist, wgts);

    // fc1: 512 shared tiles (128x64) first, then up to 2048 routed tiles
    fc1_all<<<512 + 2048, 256, 0, stream>>>(
        xb, w11, w33, sw1, sw3, h, hs, counts, toklist);

    if (DENSE) {
        fc2_all<0><<<256 + 2048, 256, 0, stream>>>(
            h, hs, w22, sw2, yexp, out, counts, toklist, wgts);
        combine_kernel<<<2048, 256, 0, stream>>>((const float4*)yexp, (float4*)out, n4x);
    } else {
        // fallback: shared overwrites out first, then routed atomically adds
        fc2_all<1><<<256, 256, 0, stream>>>(
            h, hs, w22, sw2, nullptr, out, counts, toklist, wgts);
        fc2_all<2><<<2048, 256, 0, stream>>>(
            h, hs, w22, sw2, nullptr, out, counts, toklist, wgts);
    }
}

// Round 16
// 1036.014 us; speedup vs baseline: 1.0050x; 1.0050x over previous
//
#include <hip/hip_runtime.h>
#include <hip/hip_bf16.h>

#define T_TOK  2048
#define DIMSZ  2048
#define NEXP   32
#define INTERS 1024
#define SINTER 2048
#define NTOPK  6

typedef __bf16 bf16x8 __attribute__((ext_vector_type(8)));
typedef float  f32x4  __attribute__((ext_vector_type(4)));
typedef unsigned short u16x8 __attribute__((ext_vector_type(8)));

__device__ __forceinline__ unsigned short f2b(float f) {
    __hip_bfloat16 h = __float2bfloat16(f);
    return __builtin_bit_cast(unsigned short, h);
}

// async global->LDS, 16B per lane. LDS dest is wave-uniform base + lane*16.
__device__ __forceinline__ void gl_lds16(const unsigned short* g, unsigned short* l) {
    __builtin_amdgcn_global_load_lds(
        (const __attribute__((address_space(1))) void*)g,
        (__attribute__((address_space(3))) void*)l, 16, 0, 0);
}
__device__ __forceinline__ void gl_lds16f(const float* g, float* l) {
    __builtin_amdgcn_global_load_lds(
        (const __attribute__((address_space(1))) void*)g,
        (__attribute__((address_space(3))) void*)l, 16, 0, 0);
}

// 8 f32 -> bf16x8 fragment
__device__ __forceinline__ bf16x8 cvt8(float4 lo, float4 hi) {
    u16x8 u;
    u[0] = f2b(lo.x); u[1] = f2b(lo.y); u[2] = f2b(lo.z); u[3] = f2b(lo.w);
    u[4] = f2b(hi.x); u[5] = f2b(hi.y); u[6] = f2b(hi.z); u[7] = f2b(hi.w);
    return __builtin_bit_cast(bf16x8, u);
}

// ---------------- x -> bf16 (only conversion pass, 16 MB) ----------------
__global__ void cvt_f2b(const float4* __restrict__ src, unsigned short* __restrict__ dst, int n8) {
    int stride = gridDim.x * blockDim.x;
    for (int i = blockIdx.x * blockDim.x + threadIdx.x; i < n8; i += stride) {
        float4 a = src[2 * (size_t)i];
        float4 b = src[2 * (size_t)i + 1];
        u16x8 o;
        o[0] = f2b(a.x); o[1] = f2b(a.y); o[2] = f2b(a.z); o[3] = f2b(a.w);
        o[4] = f2b(b.x); o[5] = f2b(b.y); o[6] = f2b(b.z); o[7] = f2b(b.w);
        *(u16x8*)&dst[(size_t)i * 8] = o;
    }
}

// ---------------- gate scores: scores[T,E] = sigmoid(x @ gw^T), fp32 ----------------
#define SCT 8
#define SCK 128
__global__ __launch_bounds__(256) void gate_scores_kernel(
    const float* __restrict__ x, const float* __restrict__ gw, float* __restrict__ scores)
{
    __shared__ float xs[SCT * SCK];            // 8 x 128
    __shared__ float gs[NEXP * (SCK + 1)];     // 32 x 129 (pad: conflict-free)
    const int t0 = blockIdx.x * SCT;
    const int tid = threadIdx.x;
    const int tl = tid >> 5, e = tid & 31;
    float acc = 0.f;
    for (int k0 = 0; k0 < DIMSZ; k0 += SCK) {
        {
            int row = tid >> 5, d4 = tid & 31;
            *(float4*)&xs[row * SCK + d4 * 4] =
                *(const float4*)&x[(size_t)(t0 + row) * DIMSZ + k0 + d4 * 4];
        }
        #pragma unroll
        for (int i = 0; i < 4; ++i) {
            int lin = tid + i * 256;
            int row = lin >> 5, d4 = lin & 31;
            float4 v = *(const float4*)&gw[(size_t)row * DIMSZ + k0 + d4 * 4];
            float* dst = &gs[row * (SCK + 1) + d4 * 4];
            dst[0] = v.x; dst[1] = v.y; dst[2] = v.z; dst[3] = v.w;
        }
        __syncthreads();
        #pragma unroll 8
        for (int d = 0; d < SCK; ++d)
            acc += xs[tl * SCK + d] * gs[e * (SCK + 1) + d];
        __syncthreads();
    }
    scores[(size_t)(t0 + tl) * NEXP + e] = 1.f / (1.f + expf(-acc));
}

// ---------------- top-k routing (one thread per token) ----------------
__global__ __launch_bounds__(256) void topk_kernel(
    const float* __restrict__ scores,
    int* __restrict__ counts, int* __restrict__ toklist, float* __restrict__ wgts)
{
    int t = blockIdx.x * 256 + threadIdx.x;
    if (t >= T_TOK) return;
    float sc[NEXP];
    #pragma unroll
    for (int e = 0; e < NEXP; ++e) sc[e] = scores[(size_t)t * NEXP + e];

    float gsc[8];
    #pragma unroll
    for (int g = 0; g < 8; ++g) {
        float m = sc[4 * g];
        #pragma unroll
        for (int j = 1; j < 4; ++j) m = fmaxf(m, sc[4 * g + j]);
        gsc[g] = m;
    }
    bool gsel[8] = {false, false, false, false, false, false, false, false};
    for (int it = 0; it < 4; ++it) {
        int bi = -1; float bv = -1e30f;
        #pragma unroll
        for (int g = 0; g < 8; ++g)
            if (!gsel[g] && gsc[g] > bv) { bv = gsc[g]; bi = g; }
        gsel[bi] = true;
    }
    bool esel[NEXP];
    #pragma unroll
    for (int e = 0; e < NEXP; ++e) esel[e] = false;
    int   idx[NTOPK];
    float w[NTOPK];
    float sum = 0.f;
    for (int it = 0; it < NTOPK; ++it) {
        int bi = -1; float bv = -1e30f;
        #pragma unroll
        for (int e = 0; e < NEXP; ++e) {
            if (!gsel[e >> 2] || esel[e]) continue;
            if (sc[e] > bv) { bv = sc[e]; bi = e; }
        }
        esel[bi] = true; idx[it] = bi; w[it] = bv; sum += bv;
    }
    float scale = 2.5f / sum;
    for (int k = 0; k < NTOPK; ++k) {
        int e = idx[k];
        int s = atomicAdd(&counts[e], 1);
        toklist[e * T_TOK + s] = (t << 3) | k;
        wgts[e * T_TOK + s]   = w[k] * scale;
    }
}

// routed decode walk over counts: tile (e, fy) for linear y-tile index ty,
// plus packed-h row base (sum of counts of preceding experts).
__device__ __forceinline__ void walk_experts(
    int ty, const int* __restrict__ counts, int& fe, int& fy, int& frb)
{
    int acc2 = 0, rb = 0;
    fe = -1; fy = 0; frb = 0;
    #pragma unroll
    for (int e2 = 0; e2 < NEXP; ++e2) {
        const int cnt = counts[e2];
        const int nt = (cnt + 127) >> 7;
        if (fe < 0 && ty < acc2 + nt) { fe = e2; fy = ty - acc2; frb = rb; }
        acc2 += nt; rb += cnt;
    }
}

// =======================================================================
// fc1_all: round-14 structure (tile 128x64, wave grid 2x2, 64-reg acc,
// BK=64, LDS 48 KB, 3 blocks/CU). CHANGE: H stored EXPERT-PACKED
// (row = prefix[e] + expert-local index) -> contiguous panel stores,
// no toklist read in the epilogue.
// H = silu(A@B1^T) * (A@B2^T), bf16 out.
// =======================================================================
__global__ __launch_bounds__(256, 3) void fc1_all(
    const unsigned short* __restrict__ A,
    const float* __restrict__ w11, const float* __restrict__ w33,
    const float* __restrict__ sw1, const float* __restrict__ sw3,
    unsigned short* __restrict__ h, unsigned short* __restrict__ hs,
    const int* __restrict__ counts, const int* __restrict__ toklist)
{
    constexpr int BK = 64, K = DIMSZ, NT = K / BK;
    __shared__ unsigned short As[128 * 64];   // 16 KB
    __shared__ float B1s[64 * 64];            // 16 KB
    __shared__ float B2s[64 * 64];            // 16 KB

    const int tid = threadIdx.x;
    bool SH; int e, m0, n0, hbase = 0;
    {
        const int wgid = blockIdx.x;
        if (wgid < 512) {            // shared: 16y x 32x tiles of 128x64
            SH = true; e = NEXP; m0 = (wgid >> 5) * 128; n0 = (wgid & 31) * 64;
        } else {                     // routed: 16 x-tiles of 64, expert-major
            const int rid = wgid - 512;
            const int xt = rid & 15, ty = rid >> 4;
            int fe, fy, frb;
            walk_experts(ty, counts, fe, fy, frb);
            SH = false; e = fe; m0 = fy * 128; n0 = xt * 64; hbase = frb;
        }
    }
    if (!SH && e < 0) return;
    const int N = SH ? SINTER : INTERS;
    const int M = SH ? T_TOK : counts[e];

    const size_t eoff = SH ? 0 : (size_t)e * INTERS * DIMSZ;
    const float* B1 = (SH ? sw1 : w11) + eoff + (size_t)n0 * K;
    const float* B2 = (SH ? sw3 : w33) + eoff + (size_t)n0 * K;
    unsigned short* Hout = SH ? hs : h;

    const int wave = tid >> 6;
    const int lane = tid & 63;
    const int wm = (wave >> 1) * 64;          // 2x2 wave grid over 128x64
    const int wn = (wave & 1) * 32;
    const int lm = lane & 15;
    const int quad = lane >> 4;

    // A: 16 chunks of 8 rows x 64 bf16; 4 per wave (gather xb rows by token)
    const unsigned short* aP[4];
    {
        const int l8 = lane >> 3;
        const int sg = (lane & 7) ^ l8;       // pre-swizzled 16B granule
        #pragma unroll
        for (int i = 0; i < 4; ++i) {
            const int row = (wave * 4 + i) * 8 + l8;
            const int gr = m0 + row;
            int ar;
            if (SH) ar = gr;
            else ar = (gr < M) ? (toklist[e * T_TOK + gr] >> 3) : 0;
            aP[i] = A + (size_t)ar * K + sg * 8;
        }
    }
    // B: 16 chunks of 4 rows x 64 f32; 4 per wave
    int offB[4];
    {
        #pragma unroll
        for (int i = 0; i < 4; ++i) {
            const int c = wave * 4 + i;
            const int row = 4 * c + (lane >> 4);
            const int g = (lane & 15) ^ (row & 7);
            offB[i] = row * K + g * 4;
        }
    }

    f32x4 acc1[4][2] = {};
    f32x4 acc2v[4][2] = {};

    for (int t = 0; t < NT; ++t) {
        const int k0 = t * BK;
        #pragma unroll
        for (int i = 0; i < 4; ++i)
            gl_lds16(aP[i] + k0, &As[(wave * 4 + i) * 512]);
        #pragma unroll
        for (int i = 0; i < 4; ++i) {
            gl_lds16f(B1 + offB[i] + k0, &B1s[(wave * 4 + i) * 256]);
            gl_lds16f(B2 + offB[i] + k0, &B2s[(wave * 4 + i) * 256]);
        }
        __syncthreads();   // drains vmcnt(0): all DMA visible

        #pragma unroll
        for (int kh = 0; kh < 2; ++kh) {
            const int soffA = (((kh << 2) | quad) ^ (lm & 7)) << 3;
            const int j0 = ((kh << 2) | quad) << 1;
            const int s0 = j0 ^ (lm & 7);
            const int s1 = (j0 | 1) ^ (lm & 7);
            bf16x8 af[4], bf1[2], bf2[2];
            #pragma unroll
            for (int ti = 0; ti < 4; ++ti)
                af[ti] = *(const bf16x8*)&As[(wm + ti * 16 + lm) * 64 + soffA];
            #pragma unroll
            for (int tj = 0; tj < 2; ++tj) {
                const int rB = (wn + tj * 16 + lm) * 64;
                bf1[tj] = cvt8(*(const float4*)&B1s[rB + s0 * 4],
                               *(const float4*)&B1s[rB + s1 * 4]);
                bf2[tj] = cvt8(*(const float4*)&B2s[rB + s0 * 4],
                               *(const float4*)&B2s[rB + s1 * 4]);
            }
            #pragma unroll
            for (int ti = 0; ti < 4; ++ti)
                #pragma unroll
                for (int tj = 0; tj < 2; ++tj) {
                    acc1[ti][tj] = __builtin_amdgcn_mfma_f32_16x16x32_bf16(
                        af[ti], bf1[tj], acc1[ti][tj], 0, 0, 0);
                    acc2v[ti][tj] = __builtin_amdgcn_mfma_f32_16x16x32_bf16(
                        af[ti], bf2[tj], acc2v[ti][tj], 0, 0, 0);
                }
        }
        __syncthreads();
    }

    #pragma unroll
    for (int ti = 0; ti < 4; ++ti) {
        #pragma unroll
        for (int r = 0; r < 4; ++r) {
            const int lrow = wm + ti * 16 + quad * 4 + r;
            const int grow = m0 + lrow;
            if (!SH && grow >= M) continue;
            const int cr = SH ? grow : (hbase + grow);   // expert-packed
            #pragma unroll
            for (int tj = 0; tj < 2; ++tj) {
                int nn = n0 + wn + tj * 16 + lm;
                float g = acc1[ti][tj][r];
                float u = acc2v[ti][tj][r];
                float hv = g / (1.f + expf(-g)) * u;
                Hout[(size_t)cr * N + nn] = f2b(hv);
            }
        }
    }
}

// =======================================================================
// fc2_all: round-13 BK=32 body (best-known). CHANGE: routed A reads the
// expert-packed h (ar = hbase + gr, fully contiguous, no toklist gather).
// Epilogue keeps toklist for output slot + weight.
// MODE 0: merged dense (shared->out, routed->yexp slot).
// MODE 1: shared only.  MODE 2: routed only, atomic into out.
// =======================================================================
template <int MODE>
__global__ __launch_bounds__(256, 3) void fc2_all(
    const unsigned short* __restrict__ h, const unsigned short* __restrict__ hs,
    const float* __restrict__ w22, const float* __restrict__ sw2,
    float* __restrict__ yexp, float* __restrict__ out,
    const int* __restrict__ counts, const int* __restrict__ toklist,
    const float* __restrict__ wgts)
{
    constexpr int BK = 32;
    __shared__ unsigned short As[128 * 32];   // 8 KB
    __shared__ float Bs[128 * 32];            // 16 KB

    const int tid = threadIdx.x;
    bool SH; int e, m0, n0, hbase = 0;
    {
        int wgid = blockIdx.x;
        if (MODE == 1) {
            SH = true; e = NEXP; m0 = (wgid >> 4) * 128; n0 = (wgid & 15) * 128;
        } else {
            if (MODE == 2) wgid += 256;
            if (wgid < 256) {
                SH = true; e = NEXP; m0 = (wgid >> 4) * 128; n0 = (wgid & 15) * 128;
            } else {
                const int rid = wgid - 256;
                const int xt = rid & 15, ty = rid >> 4;
                int fe, fy, frb;
                walk_experts(ty, counts, fe, fy, frb);
                SH = false; e = fe; m0 = fy * 128; n0 = xt * 128; hbase = frb;
            }
        }
    }
    if (!SH && e < 0) return;
    const int K = SH ? SINTER : INTERS;
    const int NT = K / BK;
    const int M = SH ? T_TOK : counts[e];
    if (m0 >= M) return;

    const unsigned short* Asrc = SH ? hs : h;   // row stride == K
    const float* B = (SH ? sw2 : (w22 + (size_t)e * DIMSZ * INTERS)) + (size_t)n0 * K;
    float* C = SH ? out : ((MODE == 2) ? out : yexp);

    const int wave = tid >> 6;
    const int lane = tid & 63;
    const int wm = (wave >> 1) * 64;
    const int wn = (wave & 1) * 64;
    const int lm = lane & 15;
    const int quad = lane >> 4;

    const unsigned short* aP[2];
    {
        const int gs = (lane & 3) ^ ((lane >> 3) & 3);
        #pragma unroll
        for (int i = 0; i < 2; ++i) {
            const int row = (wave * 2 + i) * 16 + (lane >> 2);
            const int gr = m0 + row;
            int ar;
            if (SH) ar = gr;
            else ar = hbase + ((gr < M) ? gr : 0);   // packed, contiguous
            aP[i] = Asrc + (size_t)ar * K + gs * 8;
        }
    }
    int offB[4];
    {
        const int gs = (lane & 7) ^ (lane >> 3);
        #pragma unroll
        for (int i = 0; i < 4; ++i) {
            const int row = (wave * 4 + i) * 8 + (lane >> 3);
            offB[i] = row * K + gs * 4;
        }
    }

    f32x4 acc[4][4] = {};

    const int ga = quad ^ ((lm >> 1) & 3);
    const int s0 = (quad << 1) ^ (lm & 7);
    const int s1 = s0 ^ 1;

    for (int t = 0; t < NT; ++t) {
        const int k0 = t * BK;
        #pragma unroll
        for (int i = 0; i < 2; ++i)
            gl_lds16(aP[i] + k0, &As[(wave * 2 + i) * 512]);
        #pragma unroll
        for (int i = 0; i < 4; ++i)
            gl_lds16f(B + offB[i] + k0, &Bs[(wave * 4 + i) * 256]);
        __syncthreads();

        bf16x8 af[4], bfr[4];
        #pragma unroll
        for (int ti = 0; ti < 4; ++ti)
            af[ti] = *(const bf16x8*)&As[(wm + ti * 16 + lm) * 32 + ga * 8];
        #pragma unroll
        for (int tj = 0; tj < 4; ++tj) {
            const int rB = (wn + tj * 16 + lm) * 32;
            bfr[tj] = cvt8(*(const float4*)&Bs[rB + s0 * 4],
                           *(const float4*)&Bs[rB + s1 * 4]);
        }
        #pragma unroll
        for (int ti = 0; ti < 4; ++ti)
            #pragma unroll
            for (int tj = 0; tj < 4; ++tj)
                acc[ti][tj] = __builtin_amdgcn_mfma_f32_16x16x32_bf16(
                    af[ti], bfr[tj], acc[ti][tj], 0, 0, 0);

        __syncthreads();
    }

    #pragma unroll
    for (int ti = 0; ti < 4; ++ti) {
        #pragma unroll
        for (int r = 0; r < 4; ++r) {
            const int lrow = wm + ti * 16 + quad * 4 + r;
            const int grow = m0 + lrow;
            int cr; float cw;
            if (SH) { cr = grow; cw = 1.f; }
            else {
                if (grow >= M) continue;
                int ent = toklist[e * T_TOK + grow];
                cr = (MODE == 2) ? (ent >> 3) : ((ent >> 3) * NTOPK + (ent & 7));
                cw = wgts[e * T_TOK + grow];
            }
            #pragma unroll
            for (int tj = 0; tj < 4; ++tj) {
                int nn = n0 + wn + tj * 16 + lm;
                float v = acc[ti][tj][r] * cw;
                if (MODE == 2 && !SH)
                    atomicAdd(&C[(size_t)cr * DIMSZ + nn], v);
                else
                    C[(size_t)cr * DIMSZ + nn] = v;
            }
        }
    }
}

// ---------------- combine: out[t,:] += sum_k yexp[t*6+k,:] ----------------
__global__ __launch_bounds__(256) void combine_kernel(
    const float4* __restrict__ yexp, float4* __restrict__ out, int n4)
{
    const int D4 = DIMSZ / 4;   // 512
    int stride = gridDim.x * blockDim.x;
    for (int i = blockIdx.x * blockDim.x + threadIdx.x; i < n4; i += stride) {
        int t = i / D4, d4 = i - t * D4;
        const float4* r = yexp + (size_t)t * NTOPK * D4 + d4;
        float4 a = out[i];
        #pragma unroll
        for (int k = 0; k < NTOPK; ++k) {
            float4 s = r[(size_t)k * D4];
            a.x += s.x; a.y += s.y; a.z += s.z; a.w += s.w;
        }
        out[i] = a;
    }
}

extern "C" void kernel_launch(void* const* d_in, const int* in_sizes, int n_in,
                              void* d_out, int out_size, void* d_ws, size_t ws_size,
                              hipStream_t stream)
{
    const float* x   = (const float*)d_in[0];
    const float* gw  = (const float*)d_in[1];
    const float* w11 = (const float*)d_in[2];
    const float* w33 = (const float*)d_in[3];
    const float* w22 = (const float*)d_in[4];
    const float* sw1 = (const float*)d_in[5];
    const float* sw2 = (const float*)d_in[6];
    const float* sw3 = (const float*)d_in[7];
    float* out = (float*)d_out;

    char* ws = (char*)d_ws;
    size_t off = 0;
    auto alloc = [&](size_t b) { void* p = ws + off; off = (off + b + 255) & ~(size_t)255; return p; };
    int*            counts  = (int*)alloc(NEXP * 4);
    int*            toklist = (int*)alloc((size_t)NEXP * T_TOK * 4);
    float*          wgts    = (float*)alloc((size_t)NEXP * T_TOK * 4);
    float*          scores  = (float*)alloc((size_t)T_TOK * NEXP * 4);
    unsigned short* xb      = (unsigned short*)alloc((size_t)T_TOK * DIMSZ * 2);
    // expert-packed h: exactly T_TOK*NTOPK rows of INTERS (+128-row guard)
    unsigned short* h       = (unsigned short*)alloc(((size_t)T_TOK * NTOPK + 128) * INTERS * 2);
    unsigned short* hs      = (unsigned short*)alloc((size_t)T_TOK * SINTER * 2);

    const size_t yBytes = (size_t)T_TOK * NTOPK * DIMSZ * 4;   // 100.7 MB
    const bool DENSE = (off + yBytes + 256) <= ws_size;
    float* yexp = DENSE ? (float*)alloc(yBytes) : nullptr;

    hipMemsetAsync(counts, 0, NEXP * 4, stream);

    const int n4x = T_TOK * DIMSZ / 4;
    cvt_f2b<<<1024, 256, 0, stream>>>((const float4*)x, xb, T_TOK * DIMSZ / 8);

    gate_scores_kernel<<<T_TOK / SCT, 256, 0, stream>>>(x, gw, scores);
    topk_kernel<<<(T_TOK + 255) / 256, 256, 0, stream>>>(scores, counts, toklist, wgts);

    // fc1: 512 shared tiles (128x64) first, then up to 2048 routed tiles
    fc1_all<<<512 + 2048, 256, 0, stream>>>(
        xb, w11, w33, sw1, sw3, h, hs, counts, toklist);

    if (DENSE) {
        fc2_all<0><<<256 + 2048, 256, 0, stream>>>(
            h, hs, w22, sw2, yexp, out, counts, toklist, wgts);
        combine_kernel<<<2048, 256, 0, stream>>>((const float4*)yexp, (float4*)out, n4x);
    } else {
        // fallback: shared overwrites out first, then routed atomically adds
        fc2_all<1><<<256, 256, 0, stream>>>(
            h, hs, w22, sw2, nullptr, out, counts, toklist, wgts);
        fc2_all<2><<<2048, 256, 0, stream>>>(
            h, hs, w22, sw2, nullptr, out, counts, toklist, wgts);
    }
}